// Round 2
// baseline (438.102 us; speedup 1.0000x reference)
//
#include <hip/hip_runtime.h>
#include <stdint.h>

// W8A8B32O32 Linear: y[m][n] = sum_k x[m][k]*w[n][k] + bias[n]
// M=8192 (B*S), N=4096 (OUT), K=4096 (IN). int32 accum/out.
// HARNESS NOTE: integer inputs arrive as int32 on device (one int per logical
// int8 element) — pack to int8 in d_ws first, then run the i8 MFMA GEMM.
#define M_TOT 8192
#define N_TOT 4096
#define K_TOT 4096

typedef int v4i  __attribute__((ext_vector_type(4)));
typedef int v16i __attribute__((ext_vector_type(16)));

__device__ __forceinline__ void gload_lds16(const void* g, void* l) {
    __builtin_amdgcn_global_load_lds(
        (const __attribute__((address_space(1))) unsigned int*)g,
        (__attribute__((address_space(3))) unsigned int*)l,
        16, 0, 0);
}

// ---- pack int32 -> int8, 16 elements/thread (read 64 B, write 16 B) ----
__global__ __launch_bounds__(256) void pack_i32_to_i8(
        const int* __restrict__ src, signed char* __restrict__ dst, int n16) {
    const int idx = blockIdx.x * 256 + threadIdx.x;
    if (idx >= n16) return;
    const int4* s = (const int4*)src;
    int4 a = s[idx * 4 + 0];
    int4 b = s[idx * 4 + 1];
    int4 c = s[idx * 4 + 2];
    int4 d = s[idx * 4 + 3];
    int4 p;
    p.x = (a.x & 255) | ((a.y & 255) << 8) | ((a.z & 255) << 16) | (a.w << 24);
    p.y = (b.x & 255) | ((b.y & 255) << 8) | ((b.z & 255) << 16) | (b.w << 24);
    p.z = (c.x & 255) | ((c.y & 255) << 8) | ((c.z & 255) << 16) | (c.w << 24);
    p.w = (d.x & 255) | ((d.y & 255) << 8) | ((d.z & 255) << 16) | (d.w << 24);
    ((int4*)dst)[idx] = p;
}

// Block tile 128x128, BK=64. 4 waves (2x2), each wave 64x64 via 2x2 frags of
// mfma_i32_32x32x32_i8. LDS tiles stored as [row][64B] with XOR chunk swizzle:
// stored_chunk = logical_chunk ^ ((row>>1)&3)  (chunk = 16B). Staging stays
// linear-in-load-order (global_load_lds needs wave-uniform LDS base + lane*16;
// the per-lane GLOBAL address is free, so the swizzle lives on the fetch side).
__global__ __launch_bounds__(256) void i8gemm_bias(
        const signed char* __restrict__ x,
        const signed char* __restrict__ w,
        const int* __restrict__ bias,
        int* __restrict__ out) {
    __shared__ __align__(16) signed char la[128 * 64];
    __shared__ __align__(16) signed char lb[128 * 64];

    const int tid  = threadIdx.x;
    const int lane = tid & 63;
    const int wave = tid >> 6;
    const int wm   = (wave >> 1) * 64;   // wave row offset in block tile
    const int wn   = (wave & 1) * 64;    // wave col offset in block tile
    const int bm0  = blockIdx.y * 128;
    const int bn0  = blockIdx.x * 128;

    const int l31 = lane & 31;
    const int kh  = lane >> 5;           // which K-half this lane supplies

    // Fused bias: init accumulator C = bias[n]; MFMA chain adds the GEMM.
    // C/D 32x32 layout: col = lane&31 (bias is lane-constant per frag).
    const int bv0 = bias[bn0 + wn + l31];
    const int bv1 = bias[bn0 + wn + 32 + l31];
    v16i acc[2][2];
#pragma unroll
    for (int i = 0; i < 2; ++i)
#pragma unroll
        for (int r = 0; r < 16; ++r) {
            acc[i][0][r] = bv0;
            acc[i][1][r] = bv1;
        }

    const signed char* ga = x + (long)bm0 * K_TOT;
    const signed char* gb = w + (long)bn0 * K_TOT;

    // Staging: tile = 128 rows x 64 B = 8192 B = 2 issues x (256 thr x 16 B).
    // Thread covers LDS linear chunk g = issue*256 + tid; it fetches the
    // global chunk whose logical col is (g&3) ^ ((row>>1)&3).
    int srow[2];
    int scol[2];
    signed char* lwa[2];
    signed char* lwb[2];
#pragma unroll
    for (int i = 0; i < 2; ++i) {
        const int g = i * 256 + tid;
        srow[i] = g >> 2;
        scol[i] = ((g & 3) ^ ((srow[i] >> 1) & 3)) * 16;
        lwa[i] = la + i * 4096 + wave * 1024;  // wave-uniform; HW adds lane*16
        lwb[i] = lb + i * 4096 + wave * 1024;
    }

    const int arow[2] = { wm + l31, wm + 32 + l31 };
    const int brow[2] = { wn + l31, wn + 32 + l31 };

    for (int kt = 0; kt < K_TOT / 64; ++kt) {
        const int k0 = kt * 64;
        __syncthreads();  // previous tile fully consumed before overwrite
#pragma unroll
        for (int i = 0; i < 2; ++i) {
            gload_lds16(ga + (long)srow[i] * K_TOT + k0 + scol[i], lwa[i]);
            gload_lds16(gb + (long)srow[i] * K_TOT + k0 + scol[i], lwb[i]);
        }
        __syncthreads();  // staging drained (compiler emits vmcnt(0) here)

        // A-operand 32x32x32_i8: m = lane&31, k = (lane>>5)*16 + byte.
        // A lane reads 16 contiguous K-bytes at logical chunk kk*2 + kh.
        v4i af[2][2], bf[2][2];  // [frag][kk]
#pragma unroll
        for (int i = 0; i < 2; ++i) {
            const int raA = arow[i];
            const int swA = (raA >> 1) & 3;
            const int raB = brow[i];
            const int swB = (raB >> 1) & 3;
#pragma unroll
            for (int kk = 0; kk < 2; ++kk) {
                const int cA = ((kk * 2 + kh) ^ swA) * 16;
                const int cB = ((kk * 2 + kh) ^ swB) * 16;
                af[i][kk] = *(const v4i*)(la + raA * 64 + cA);
                bf[i][kk] = *(const v4i*)(lb + raB * 64 + cB);
            }
        }

#pragma unroll
        for (int kk = 0; kk < 2; ++kk)
#pragma unroll
            for (int i = 0; i < 2; ++i)
#pragma unroll
                for (int j = 0; j < 2; ++j)
                    acc[i][j] = __builtin_amdgcn_mfma_i32_32x32x32_i8(
                        af[i][kk], bf[j][kk], acc[i][j], 0, 0, 0);
    }

    // Epilogue: C/D 32x32 layout col=lane&31, row=(reg&3)+8*(reg>>2)+4*(lane>>5).
#pragma unroll
    for (int i = 0; i < 2; ++i) {
        const int mbase = bm0 + wm + i * 32 + 4 * kh;
#pragma unroll
        for (int j = 0; j < 2; ++j) {
            const int n = bn0 + wn + j * 32 + l31;
#pragma unroll
            for (int r = 0; r < 16; ++r) {
                const int m = mbase + (r & 3) + 8 * (r >> 2);
                out[(long)m * N_TOT + n] = acc[i][j][r];
            }
        }
    }
}

extern "C" void kernel_launch(void* const* d_in, const int* in_sizes, int n_in,
                              void* d_out, int out_size, void* d_ws, size_t ws_size,
                              hipStream_t stream) {
    const int* x32  = (const int*)d_in[0];  // [8192, 4096] logical i8, stored i32
    const int* w32  = (const int*)d_in[1];  // [4096, 4096] logical i8, stored i32
    const int* bias = (const int*)d_in[2];  // [4096] i32
    int*       out  = (int*)d_out;          // [8192, 4096] i32

    signed char* xp = (signed char*)d_ws;                    // 33554432 B
    signed char* wp = (signed char*)d_ws + (size_t)M_TOT * K_TOT;  // 16777216 B

    const int n16x = (M_TOT * K_TOT) / 16;  // 2097152
    const int n16w = (N_TOT * K_TOT) / 16;  // 1048576
    pack_i32_to_i8<<<n16x / 256, 256, 0, stream>>>(x32, xp, n16x);
    pack_i32_to_i8<<<n16w / 256, 256, 0, stream>>>(w32, wp, n16w);

    dim3 grid(N_TOT / 128, M_TOT / 128);  // (32, 64)
    i8gemm_bias<<<grid, 256, 0, stream>>>(xp, wp, bias, out);
}

// Round 3
// 415.160 us; speedup vs baseline: 1.0553x; 1.0553x over previous
//
#include <hip/hip_runtime.h>
#include <stdint.h>

// W8A8B32O32 Linear: y[m][n] = sum_k x[m][k]*w[n][k] + bias[n]
// M=8192, N=4096, K=4096. Inputs arrive as int32 (one int per logical int8
// element); pack to int8 in d_ws, then run the i8 MFMA GEMM.
#define M_TOT 8192
#define N_TOT 4096
#define K_TOT 4096

typedef int v4i  __attribute__((ext_vector_type(4)));
typedef int v16i __attribute__((ext_vector_type(16)));

__device__ __forceinline__ void gload_lds16(const void* g, void* l) {
    __builtin_amdgcn_global_load_lds(
        (const __attribute__((address_space(1))) unsigned int*)g,
        (__attribute__((address_space(3))) unsigned int*)l,
        16, 0, 0);
}

// ---- pack int32 -> int8, 4 elements/thread, fully coalesced -------------
// Read: int4 (16 B/lane, lane-contiguous). Write: int (4 B/lane, contiguous).
__global__ __launch_bounds__(256) void pack_i32_to_i8(
        const int4* __restrict__ src, int* __restrict__ dst, int n4) {
    const int idx = blockIdx.x * 256 + threadIdx.x;
    if (idx >= n4) return;
    const int4 a = src[idx];
    dst[idx] = (a.x & 255) | ((a.y & 255) << 8) | ((a.z & 255) << 16) | (a.w << 24);
}

// ---- GEMM: 64-thread block = 1 wave computing a 128x128 tile ------------
// BK=64 bytes. 4x4 fragments of mfma_i32_32x32x32_i8 (acc 256 VGPR, 1
// wave/SIMD -> 4 independent blocks/CU give implicit stage/compute overlap).
// LDS-BW analysis: 8 ds_read_b128 feed 16 MFMAs per kk (512 B/MFMA), twice
// the intensity of the 64x64-wave-tile version (was the binding constraint).
// XOR chunk swizzle: stored_chunk = logical_chunk ^ ((row>>1)&3); staging
// stays linear-in-load-order (global_load_lds needs wave-uniform LDS base).
__global__ __launch_bounds__(64, 1) void i8gemm_bias(
        const signed char* __restrict__ x,
        const signed char* __restrict__ w,
        const int* __restrict__ bias,
        int* __restrict__ out) {
    __shared__ __align__(16) signed char la[128 * 64];
    __shared__ __align__(16) signed char lb[128 * 64];

    const int lane = threadIdx.x;        // 0..63
    const int l31  = lane & 31;
    const int kh   = lane >> 5;          // K-half this lane supplies to MFMA
    const int bm0  = blockIdx.y * 128;
    const int bn0  = blockIdx.x * 128;

    // Fused bias: C/D col = lane&31 -> bias is lane-constant per fragment.
    int bv[4];
#pragma unroll
    for (int j = 0; j < 4; ++j) bv[j] = bias[bn0 + j * 32 + l31];
    v16i acc[4][4];
#pragma unroll
    for (int i = 0; i < 4; ++i)
#pragma unroll
        for (int j = 0; j < 4; ++j)
#pragma unroll
            for (int r = 0; r < 16; ++r) acc[i][j][r] = bv[j];

    // Staging: tile 128 rows x 64 B = 8 issues x (64 lanes x 16 B).
    // Issue i covers LDS chunks [i*64, i*64+64): row = i*16 + (lane>>2),
    // stored chunk = lane&3. Fetch chunk = (lane&3) ^ ((row>>1)&3); since
    // (i*16)>>1 is a multiple of 8, swizzle = (lane>>3)&3, issue-invariant.
    const int fc = (lane & 3) ^ ((lane >> 3) & 3);
    const signed char* pa = x + (long)(bm0 + (lane >> 2)) * K_TOT + fc * 16;
    const signed char* pb = w + (long)(bn0 + (lane >> 2)) * K_TOT + fc * 16;

    // Fragment reads: row = i*32 + l31; swizzle = ((i*32+l31)>>1)&3 =
    // (l31>>1)&3, fragment- and operand-invariant.
    const int swr = (l31 >> 1) & 3;

    for (int kt = 0; kt < K_TOT / 64; ++kt) {
        const long k0 = (long)kt * 64;
        __syncthreads();  // previous tile's reads fully consumed
#pragma unroll
        for (int i = 0; i < 8; ++i) {
            gload_lds16(pa + k0 + (long)i * 16 * K_TOT, la + i * 1024);
            gload_lds16(pb + k0 + (long)i * 16 * K_TOT, lb + i * 1024);
        }
        __syncthreads();  // staging drained (vmcnt) before fragment reads

#pragma unroll
        for (int kk = 0; kk < 2; ++kk) {
            // A/B operand 32x32x32_i8: m(n) = lane&31, k = (lane>>5)*16+byte
            // -> lane reads 16 contiguous bytes at logical chunk kk*2 + kh.
            const int cs = ((kk * 2 + kh) ^ swr) * 16;
            v4i af[4], bf[4];
#pragma unroll
            for (int i = 0; i < 4; ++i) {
                af[i] = *(const v4i*)(la + (i * 32 + l31) * 64 + cs);
                bf[i] = *(const v4i*)(lb + (i * 32 + l31) * 64 + cs);
            }
#pragma unroll
            for (int i = 0; i < 4; ++i)
#pragma unroll
                for (int j = 0; j < 4; ++j)
                    acc[i][j] = __builtin_amdgcn_mfma_i32_32x32x32_i8(
                        af[i], bf[j], acc[i][j], 0, 0, 0);
        }
    }

    // Epilogue: C/D layout col=lane&31, row=(reg&3)+8*(reg>>2)+4*(lane>>5).
#pragma unroll
    for (int i = 0; i < 4; ++i) {
        const int mbase = bm0 + i * 32 + 4 * kh;
#pragma unroll
        for (int j = 0; j < 4; ++j) {
            const int n = bn0 + j * 32 + l31;
#pragma unroll
            for (int r = 0; r < 16; ++r) {
                const int m = mbase + (r & 3) + 8 * (r >> 2);
                out[(long)m * N_TOT + n] = acc[i][j][r];
            }
        }
    }
}

extern "C" void kernel_launch(void* const* d_in, const int* in_sizes, int n_in,
                              void* d_out, int out_size, void* d_ws, size_t ws_size,
                              hipStream_t stream) {
    const int* x32  = (const int*)d_in[0];  // [8192,4096] logical i8 as i32
    const int* w32  = (const int*)d_in[1];  // [4096,4096] logical i8 as i32
    const int* bias = (const int*)d_in[2];  // [4096] i32
    int*       out  = (int*)d_out;          // [8192,4096] i32

    signed char* xp = (signed char*)d_ws;
    signed char* wp = (signed char*)d_ws + (size_t)M_TOT * K_TOT;

    const int n4x = (M_TOT * K_TOT) / 4;  // 8388608
    const int n4w = (N_TOT * K_TOT) / 4;  // 4194304
    pack_i32_to_i8<<<n4x / 256, 256, 0, stream>>>((const int4*)x32, (int*)xp, n4x);
    pack_i32_to_i8<<<n4w / 256, 256, 0, stream>>>((const int4*)w32, (int*)wp, n4w);

    dim3 grid(N_TOT / 128, M_TOT / 128);  // (32, 64)
    i8gemm_bias<<<grid, 64, 0, stream>>>(xp, wp, bias, out);
}

// Round 5
// 412.347 us; speedup vs baseline: 1.0625x; 1.0068x over previous
//
#include <hip/hip_runtime.h>
#include <stdint.h>

// W8A8B32O32 Linear: y[m][n] = sum_k x[m][k]*w[n][k] + bias[n]
// M=8192, N=4096, K=4096. Inputs arrive as int32 (one int per logical int8
// element); pack to int8 in d_ws, then run the i8 MFMA GEMM.
#define M_TOT 8192
#define N_TOT 4096
#define K_TOT 4096

typedef int v4i  __attribute__((ext_vector_type(4)));
typedef int v16i __attribute__((ext_vector_type(16)));

__device__ __forceinline__ void gload_lds16(const void* g, void* l) {
    __builtin_amdgcn_global_load_lds(
        (const __attribute__((address_space(1))) unsigned int*)g,
        (__attribute__((address_space(3))) unsigned int*)l,
        16, 0, 0);
}

// s_waitcnt vmcnt(0) only: gfx9 simm16 = vmcnt[3:0]|[15:14]=0,
// expcnt[6:4]=7, lgkmcnt[11:8]=15 -> 0x0f70.
#define WAIT_VMCNT0() __builtin_amdgcn_s_waitcnt(0x0f70)

// ---- pack int32 -> int8, coalesced (16B load / 4B store per lane), 4x ----
__global__ __launch_bounds__(256) void pack_i32_to_i8(
        const int4* __restrict__ src, int* __restrict__ dst, int n4) {
    int idx = blockIdx.x * 1024 + threadIdx.x;
#pragma unroll
    for (int u = 0; u < 4; ++u, idx += 256) {
        const int4 a = src[idx];
        dst[idx] = (a.x & 255) | ((a.y & 255) << 8) |
                   ((a.z & 255) << 16) | (a.w << 24);
    }
}

// ---- GEMM: 64-thread block = 1 wave computing a 128x128 tile ------------
// BK=64 bytes, 4x4 frags of mfma_i32_32x32x32_i8. 1 wave/SIMD: latency is
// hidden by SOFTWARE PIPELINING: double-buffered LDS, per-iteration order =
// [vmcnt(0) for cur buf] -> [ds_read frags of cur] -> [DMA-prefetch nxt]
// -> [32 MFMAs ~1170 cyc]. The vmcnt wait covers DMAs issued one full MFMA
// block earlier (> HBM latency), so it is nearly free. The explicit wait is
// REQUIRED: compiler alias analysis does not connect global_load_lds's LDS
// write to the ds_reads (round-4 absmax 3e5 race without it).
// XOR chunk swizzle: stored_chunk = logical_chunk ^ ((row>>1)&3); staging
// stays linear-in-load-order (global_load_lds needs wave-uniform LDS base).
__global__ __launch_bounds__(64, 1) void i8gemm_bias(
        const signed char* __restrict__ x,
        const signed char* __restrict__ w,
        const int* __restrict__ bias,
        int* __restrict__ out) {
    __shared__ __align__(16) signed char la[2][128 * 64];
    __shared__ __align__(16) signed char lb[2][128 * 64];

    const int lane = threadIdx.x;        // 0..63
    const int l31  = lane & 31;
    const int kh   = lane >> 5;          // K-half this lane supplies to MFMA
    const int bm0  = blockIdx.y * 128;
    const int bn0  = blockIdx.x * 128;

    // Fused bias: C/D col = lane&31 -> bias is lane-constant per fragment.
    int bv[4];
#pragma unroll
    for (int j = 0; j < 4; ++j) bv[j] = bias[bn0 + j * 32 + l31];
    v16i acc[4][4];
#pragma unroll
    for (int i = 0; i < 4; ++i)
#pragma unroll
        for (int j = 0; j < 4; ++j)
#pragma unroll
            for (int r = 0; r < 16; ++r) acc[i][j][r] = bv[j];

    // Staging: tile 128 rows x 64 B = 8 issues x (64 lanes x 16 B).
    // Issue i covers rows i*16 + (lane>>2); stored chunk = lane&3; fetch
    // chunk = (lane&3) ^ ((row>>1)&3) = (lane&3) ^ ((lane>>3)&3).
    const int fc = (lane & 3) ^ ((lane >> 3) & 3);
    const signed char* pa = x + (long)(bm0 + (lane >> 2)) * K_TOT + fc * 16;
    const signed char* pb = w + (long)(bn0 + (lane >> 2)) * K_TOT + fc * 16;

    // Fragment reads: row = i*32 + l31 -> swizzle = (l31>>1)&3, invariant.
    const int swr = (l31 >> 1) & 3;

    // Prologue: stage kt=0 into buffer 0.
#pragma unroll
    for (int i = 0; i < 8; ++i) {
        gload_lds16(pa + (long)i * 16 * K_TOT, &la[0][i * 1024]);
        gload_lds16(pb + (long)i * 16 * K_TOT, &lb[0][i * 1024]);
    }

    for (int kt = 0; kt < K_TOT / 64; ++kt) {
        const int cur = kt & 1;
        const signed char* lac = la[cur];
        const signed char* lbc = lb[cur];

        // 0) Current buffer's DMAs (issued last iteration) must have landed.
        WAIT_VMCNT0();
        __builtin_amdgcn_sched_barrier(0);

        // 1) All fragment reads of the current buffer.
        // A/B operand 32x32x32_i8: m(n)=lane&31, k=(lane>>5)*16+byte ->
        // lane reads 16 contiguous bytes at logical chunk kk*2 + kh.
        v4i af[2][4], bf[2][4];
#pragma unroll
        for (int kk = 0; kk < 2; ++kk) {
            const int cs = ((kk * 2 + kh) ^ swr) * 16;
#pragma unroll
            for (int i = 0; i < 4; ++i) {
                af[kk][i] = *(const v4i*)(lac + (i * 32 + l31) * 64 + cs);
                bf[kk][i] = *(const v4i*)(lbc + (i * 32 + l31) * 64 + cs);
            }
        }
        __builtin_amdgcn_sched_barrier(0);

        // 2) Prefetch next K-tile into the other buffer (fire-and-forget).
        if (kt + 1 < K_TOT / 64) {
            const long k0 = (long)(kt + 1) * 64;
            signed char* lan = la[cur ^ 1];
            signed char* lbn = lb[cur ^ 1];
#pragma unroll
            for (int i = 0; i < 8; ++i) {
                gload_lds16(pa + k0 + (long)i * 16 * K_TOT, lan + i * 1024);
                gload_lds16(pb + k0 + (long)i * 16 * K_TOT, lbn + i * 1024);
            }
        }
        __builtin_amdgcn_sched_barrier(0);

        // 3) Compute: 32 MFMAs (~1170 cyc of matrix pipe) cover the prefetch.
#pragma unroll
        for (int kk = 0; kk < 2; ++kk)
#pragma unroll
            for (int i = 0; i < 4; ++i)
#pragma unroll
                for (int j = 0; j < 4; ++j)
                    acc[i][j] = __builtin_amdgcn_mfma_i32_32x32x32_i8(
                        af[kk][i], bf[kk][j], acc[i][j], 0, 0, 0);
    }

    // Epilogue: C/D layout col=lane&31, row=(reg&3)+8*(reg>>2)+4*(lane>>5).
#pragma unroll
    for (int i = 0; i < 4; ++i) {
        const int mbase = bm0 + i * 32 + 4 * kh;
#pragma unroll
        for (int j = 0; j < 4; ++j) {
            const int n = bn0 + j * 32 + l31;
#pragma unroll
            for (int r = 0; r < 16; ++r) {
                const int m = mbase + (r & 3) + 8 * (r >> 2);
                out[(long)m * N_TOT + n] = acc[i][j][r];
            }
        }
    }
}

extern "C" void kernel_launch(void* const* d_in, const int* in_sizes, int n_in,
                              void* d_out, int out_size, void* d_ws, size_t ws_size,
                              hipStream_t stream) {
    const int* x32  = (const int*)d_in[0];  // [8192,4096] logical i8 as i32
    const int* w32  = (const int*)d_in[1];  // [4096,4096] logical i8 as i32
    const int* bias = (const int*)d_in[2];  // [4096] i32
    int*       out  = (int*)d_out;          // [8192,4096] i32

    signed char* xp = (signed char*)d_ws;
    signed char* wp = (signed char*)d_ws + (size_t)M_TOT * K_TOT;

    const int n4x = (M_TOT * K_TOT) / 4;  // 8388608 (divisible by 1024)
    const int n4w = (N_TOT * K_TOT) / 4;  // 4194304 (divisible by 1024)
    pack_i32_to_i8<<<n4x / 1024, 256, 0, stream>>>((const int4*)x32, (int*)xp, n4x);
    pack_i32_to_i8<<<n4w / 1024, 256, 0, stream>>>((const int4*)w32, (int*)wp, n4w);

    dim3 grid(N_TOT / 128, M_TOT / 128);  // (32, 64)
    i8gemm_bias<<<grid, 64, 0, stream>>>(xp, wp, bias, out);
}